// Round 14
// baseline (1194.650 us; speedup 1.0000x reference)
//
#include <hip/hip_runtime.h>
#include <hip/hip_bf16.h>
#include <math.h>

#define TCc 200
#define TDc 50
#define BATCH 256
#define Ec 300
#define Hc 512
#define VOC 10000
#define EPAD 320
#define KC_E 10
#define KC_H 16
#define ROT 16   // h rotation depth (L1 self-eviction window)

typedef unsigned short u16;
typedef unsigned int u32;
typedef unsigned long long u64;
typedef __bf16 bf16x8 __attribute__((ext_vector_type(8)));
typedef float f32x4 __attribute__((ext_vector_type(4)));

__device__ __forceinline__ float sigf(float x) { return 1.f / (1.f + expf(-x)); }

__device__ __forceinline__ u16 f2bf(float f) {
  unsigned u = __float_as_uint(f);
  unsigned r = (u + 0x7FFFu + ((u >> 16) & 1u)) >> 16;  // RNE
  return (u16)r;
}
__device__ __forceinline__ float bf2f(u16 v) { return __uint_as_float(((unsigned)v) << 16); }

// L2-local atomic RMW (workgroup scope: no cache-maintenance ops, executes in XCD L2)
__device__ __forceinline__ u32 l2_add(u32* p, u32 v) {
  return __hip_atomic_fetch_add(p, v, __ATOMIC_RELAXED, __HIP_MEMORY_SCOPE_WORKGROUP);
}
// sc0 = L1-bypassing, L2-served plain load/store (NOT a MALL op, NOT an RMW).
// waitcnt is INSIDE the asm so the "=v" result is valid at retire (rule-of-round-8).
__device__ __forceinline__ u32 ld_l2(const u32* p) {
  u32 v;
  asm volatile("global_load_dword %0, %1, off sc0\n\ts_waitcnt vmcnt(0)"
               : "=v"(v) : "v"(p) : "memory");
  return v;
}
__device__ __forceinline__ void st_l2(u32* p, u32 v) {
  asm volatile("global_store_dword %0, %1, off sc0" :: "v"(p), "v"(v) : "memory");
}

__global__ __launch_bounds__(256) void zero_kernel(float* p, int n) {
  int i = blockIdx.x * 256 + threadIdx.x;
  if (i < n) p[i] = 0.f;
}

// emb (VOC, Ec) fp32 -> (VOC, EPAD) bf16, zero-padded
__global__ __launch_bounds__(256) void conv_emb_kernel(
    const float* __restrict__ emb, u32* __restrict__ out)
{
  int e = blockIdx.x * 256 + threadIdx.x;          // u32 index, VOC*EPAD/2 total
  if (e >= VOC * (EPAD / 2)) return;
  int v = e / (EPAD / 2);
  int k = (e - v * (EPAD / 2)) * 2;
  float a = (k < Ec) ? emb[(size_t)v * Ec + k] : 0.f;
  float b = (k + 1 < Ec) ? emb[(size_t)v * Ec + k + 1] : 0.f;
  out[e] = (u32)f2bf(a) | ((u32)f2bf(b) << 16);
}

// Weight (rows x K) fp32 -> MFMA B-fragment order bf16 (same as round 12/13).
template<int GATES>
__global__ __launch_bounds__(256) void conv_wfrag_kernel(
    const float* __restrict__ W, u32* __restrict__ out, int KC, int KREAL, int total)
{
  int e = blockIdx.x * 256 + threadIdx.x;          // u32 index
  if (e >= total) return;
  int jp = e & 3;
  int l = (e >> 2) & 63;
  int si = (e >> 8) & 1;
  int t2 = e >> 9;
  int kc = t2 % KC;
  int nc = t2 / KC;
  int c32 = (si << 4) + (l & 15);
  int srow;
  if (GATES) {
    int ulp = c32 >> 2, g = c32 & 3;
    int unit = ((ulp & 3) << 1) | (ulp >> 2);
    srow = (g << 9) + nc * 8 + unit;
  } else {
    srow = nc * 32 + c32;
  }
  int k = (kc << 5) + ((l >> 4) << 3) + (jp << 1);
  float a = (k < KREAL) ? W[(size_t)srow * KREAL + k] : 0.f;
  float b = (k + 1 < KREAL) ? W[(size_t)srow * KREAL + k + 1] : 0.f;
  out[e] = (u32)f2bf(a) | ((u32)f2bf(b) << 16);
}

// ---------------- persistent MFMA LSTM, XCD-local rowgroups ----------------
// Rowgroup = physical XCD (all 64 blocks share one L2). h exchange via PLAIN cached
// ld/st (dirty in shared L2); L1 staleness avoided by 16-deep buffer rotation.
// Barrier: flag ARRAY — each block sc0-stores gen to its own flag line (64 parallel
// stores, no RMW); wave0's 64 lanes sc0-LOAD the 64 flags (reads don't line-lock).
__device__ __forceinline__ void bar_signal(u32* flg, int cg, u32 gen) {
  asm volatile("s_waitcnt vmcnt(0)" ::: "memory");   // h stores acked by L2
  __syncthreads();
  if (threadIdx.x == 0) st_l2(flg + (cg << 4), gen);
}
__device__ __forceinline__ void bar_wait(u32* flg, u32 gen) {
  if (threadIdx.x < 64) {
    for (;;) {
      u32 v = ld_l2(flg + ((int)threadIdx.x << 4));
      if (__all(v >= gen)) break;
      __builtin_amdgcn_s_sleep(1);
    }
  }
  __syncthreads();
}

struct PArgs {
  const u32* WhhT; const u32* WihT; const u16* embT;
  const u32* WhhD; const u32* WihD; const u16* embD;
  const int* tokens; const int* desc_anchor; const int* desc_neg;
  const int* desc_anchor_len; const int* desc_neg_len;
  const float* tok_bih; const float* tok_bhh;
  const float* desc_bih; const float* desc_bhh;
  u16* hTok; u16* hDesc;      // rotating fragment buffers: [rg][ROT][ROWS*512] u16
  u16* featB; float* finals;
  u32* flags;                  // [8 rg x 64 flags x 16 u32] + [8 claim x 16]
};

// cg in [0,64); rg fixed by XCD. ROWS=64 (tok) / 128 (desc). RPW = ROWS/64.
// h fragment layout per buffer: [rhp=lrow>>4][kc 16][lane 64][8 bf16].
template<int ROWS, bool IS_TOK>
__device__ void lstm_phase(
    int cg, int rg, u16* WhF, u16* WiF, float* gsum, int* idsL,
    const u32* __restrict__ WhhF, const u32* __restrict__ WihF, const u16* __restrict__ embB,
    const int* __restrict__ idsA, const int* __restrict__ idsB,
    const int* __restrict__ lenA, const int* __restrict__ lenB,
    const float* __restrict__ bih, const float* __restrict__ bhh,
    u16* __restrict__ hrot,
    u16* __restrict__ featB, float* __restrict__ finals,
    u32* flg, int T)
{
  constexpr int RPW = ROWS / 64;
  constexpr size_t BUFN = (size_t)ROWS << 9;   // u16 per rotation slot
  const int tid = threadIdx.x;
  const int row0 = rg * ROWS;
  const int w = tid >> 6, l = tid & 63;
  const int rl = tid >> 2, u = tid & 3;
  u32 gen = 0;

  // stage weight fragments into LDS
  {
    const uint4* s = (const uint4*)(WhhF + ((size_t)cg << 13));
    uint4* d = (uint4*)WhF;
    #pragma unroll
    for (int i = 0; i < 8; ++i) d[(i << 8) + tid] = s[(i << 8) + tid];
    const uint4* s2 = (const uint4*)(WihF + (size_t)cg * 5120);
    uint4* d2 = (uint4*)WiF;
    #pragma unroll
    for (int i = 0; i < 5; ++i) d2[(i << 8) + tid] = s2[(i << 8) + tid];
  }

  const int ug0 = (cg << 3) + (u << 1);   // this thread's two adjacent units
  float bsv[2][4];
  #pragma unroll
  for (int uu = 0; uu < 2; ++uu)
    #pragma unroll
    for (int g = 0; g < 4; ++g)
      bsv[uu][g] = bih[(g << 9) + ug0 + uu] + bhh[(g << 9) + ug0 + uu];

  const int kcs    = ug0 >> 5;
  const int lanehi = (ug0 >> 3) & 3;
  const int jpos   = ug0 & 7;   // even

  float cc[RPW][2];
  int lens[RPW];
  #pragma unroll
  for (int p = 0; p < RPW; ++p) {
    cc[p][0] = 0.f; cc[p][1] = 0.f;
    int lrow = (p << 6) + rl;
    int row = row0 + lrow;
    lens[p] = IS_TOK ? 0 : ((row < BATCH) ? lenA[row] : lenB[row - BATCH]);
    int rhp = lrow >> 4;
    int lane_s = (rl & 15) | (lanehi << 4);
    size_t off16 = ((((size_t)rhp << 4) + kcs) << 6 | lane_s) << 3 | jpos;
    *(u32*)(hrot + off16) = 0u;   // slot 0 = initial zeros (plain store -> L2)
  }
  ++gen; bar_signal(flg, cg, gen);   // zeros visible

  for (int t = 0; t < T; ++t) {
    const u16* hin = hrot + (size_t)(t & (ROT - 1)) * BUFN;
    u16* hout = hrot + (size_t)((t + 1) & (ROT - 1)) * BUFN;

    if (tid < ROWS) {
      int row = row0 + tid;
      idsL[tid] = IS_TOK ? idsA[row * T + t]
                         : ((row < BATCH) ? idsA[row * T + t] : idsB[(row - BATCH) * T + t]);
    }
    __syncthreads();

    f32x4 acc[RPW][2];
    #pragma unroll
    for (int p = 0; p < RPW; ++p) {
      acc[p][0] = (f32x4){0.f, 0.f, 0.f, 0.f};
      acc[p][1] = (f32x4){0.f, 0.f, 0.f, 0.f};
    }
    const u16* eb[RPW];
    const u16* hfb[RPW];
    #pragma unroll
    for (int p = 0; p < RPW; ++p) {
      int rhp = w + (p << 2);
      int ida = idsL[(rhp << 4) + (l & 15)];
      eb[p] = embB + (size_t)ida * EPAD + ((l >> 4) << 3);
      hfb[p] = hin + ((((size_t)rhp << 4) << 9) | (l << 3));   // kc stride = 512 u16
    }

    // ---- h-independent input-projection MFMAs first ----
    #pragma unroll
    for (int kc = 0; kc < KC_E; ++kc) {
      bf16x8 b0 = *(const bf16x8*)(WiF + ((((kc << 1) | 0) << 6 | l) << 3));
      bf16x8 b1 = *(const bf16x8*)(WiF + ((((kc << 1) | 1) << 6 | l) << 3));
      #pragma unroll
      for (int p = 0; p < RPW; ++p) {
        bf16x8 a = *(const bf16x8*)(eb[p] + (kc << 5));
        acc[p][0] = __builtin_amdgcn_mfma_f32_16x16x32_bf16(a, b0, acc[p][0], 0, 0, 0);
        acc[p][1] = __builtin_amdgcn_mfma_f32_16x16x32_bf16(a, b1, acc[p][1], 0, 0, 0);
      }
    }

    // ---- wait for h(t-1) visibility (L2-local flag loads) ----
    bar_wait(flg, gen);

    // ---- recurrent MFMAs from plain cached 16B loads (L2 hits, L1 safe via ROT) ----
    #pragma unroll
    for (int kc = 0; kc < KC_H; ++kc) {
      bf16x8 b0 = *(const bf16x8*)(WhF + ((((kc << 1) | 0) << 6 | l) << 3));
      bf16x8 b1 = *(const bf16x8*)(WhF + ((((kc << 1) | 1) << 6 | l) << 3));
      #pragma unroll
      for (int p = 0; p < RPW; ++p) {
        bf16x8 a = *(const bf16x8*)(hfb[p] + (kc << 9));
        acc[p][0] = __builtin_amdgcn_mfma_f32_16x16x32_bf16(a, b0, acc[p][0], 0, 0, 0);
        acc[p][1] = __builtin_amdgcn_mfma_f32_16x16x32_bf16(a, b1, acc[p][1], 0, 0, 0);
      }
    }

    // ---- epilogue: gates, c/h update; h (fragment order, plain store); feat deferred ----
    float hnv[RPW][2];
    #pragma unroll
    for (int p = 0; p < RPW; ++p) {
      int lr0 = (w << 4) + ((l >> 4) << 2);
      #pragma unroll
      for (int si = 0; si < 2; ++si)
        #pragma unroll
        for (int j = 0; j < 4; ++j)
          gsum[(lr0 + j) * 36 + (si << 4) + (l & 15)] = acc[p][si][j];
      __syncthreads();
      {
        float4 g0 = *(const float4*)&gsum[rl * 36 + (u << 2)];          // unit 2u
        float4 g1 = *(const float4*)&gsum[rl * 36 + ((u + 4) << 2)];    // unit 2u+1
        int lrow = (p << 6) + rl;
        int row = row0 + lrow;
        float gi0 = sigf(g0.x + bsv[0][0]);
        float gf0 = sigf(g0.y + bsv[0][1]);
        float gg0 = tanhf(g0.z + bsv[0][2]);
        float go0 = sigf(g0.w + bsv[0][3]);
        float cn0 = gf0 * cc[p][0] + gi0 * gg0;
        cc[p][0] = cn0;
        float hn0 = go0 * tanhf(cn0);
        float gi1 = sigf(g1.x + bsv[1][0]);
        float gf1 = sigf(g1.y + bsv[1][1]);
        float gg1 = tanhf(g1.z + bsv[1][2]);
        float go1 = sigf(g1.w + bsv[1][3]);
        float cn1 = gf1 * cc[p][1] + gi1 * gg1;
        cc[p][1] = cn1;
        float hn1 = go1 * tanhf(cn1);
        hnv[p][0] = hn0; hnv[p][1] = hn1;
        int rhp = lrow >> 4;
        int lane_s = (rl & 15) | (lanehi << 4);
        size_t off16 = ((((size_t)rhp << 4) + kcs) << 6 | lane_s) << 3 | jpos;
        *(u32*)(hout + off16) = (u32)f2bf(hn0) | ((u32)f2bf(hn1) << 16);
        if (!IS_TOK) {
          if (t == lens[p] - 1) {
            finals[((size_t)row << 9) + ug0]     = tanhf(hn0);
            finals[((size_t)row << 9) + ug0 + 1] = tanhf(hn1);
          }
        }
      }
      __syncthreads();
    }
    ++gen; bar_signal(flg, cg, gen);   // h(t) visible in L2

    if (IS_TOK) {
      #pragma unroll
      for (int p = 0; p < RPW; ++p) {
        int row = row0 + (p << 6) + rl;
        size_t fo = ((size_t)row * TCc + t) << 9;
        *(u32*)(featB + fo + ug0) =
            (u32)f2bf(tanhf(hnv[p][0])) | ((u32)f2bf(tanhf(hnv[p][1])) << 16);
      }
    }
  }
}

// 512 blocks; each claims (xcd, rank) at start. Capacity (2 blocks/CU by LDS, 32 CU/XCD)
// forces exactly 64 blocks per XCD. XCDs 0-3 -> tok rowgroups, 4-7 -> desc rowgroups.
__global__ void __launch_bounds__(256, 1) lstm_persist_kernel(PArgs A) {
  __shared__ __align__(16) u16 WhF[KC_H * 2 * 64 * 8];   // 32768 B
  __shared__ __align__(16) u16 WiF[KC_E * 2 * 64 * 8];   // 20480 B
  __shared__ __align__(16) float gsum[64 * 36];          // 9216 B
  __shared__ int idsL[128];                              // 512 B
  __shared__ int s_claim[2];
  if (threadIdx.x == 0) {
    int xcd;
    asm("s_getreg_b32 %0, hwreg(HW_REG_XCC_ID)" : "=s"(xcd));
    xcd &= 7;
    u32 rank = l2_add(A.flags + 8192 + (xcd << 4), 1u);   // claim slot (L2-local RMW)
    s_claim[0] = xcd;
    s_claim[1] = (int)rank;
  }
  __syncthreads();
  const int xcd = s_claim[0];
  const int cg = s_claim[1] & 63;

  if (xcd < 4) {
    int rg = xcd;
    u32* flg = A.flags + (rg << 10);                     // 64 flags x 16 u32
    u16* hrot = A.hTok + (size_t)rg * ROT * ((size_t)64 << 9);
    lstm_phase<64, true>(cg, rg, WhF, WiF, gsum, idsL, A.WhhT, A.WihT, A.embT,
                         A.tokens, nullptr, nullptr, nullptr,
                         A.tok_bih, A.tok_bhh, hrot, A.featB, nullptr,
                         flg, TCc);
  } else {
    int rg = xcd - 4;
    u32* flg = A.flags + ((4 + rg) << 10);
    u16* hrot = A.hDesc + (size_t)rg * ROT * ((size_t)128 << 9);
    lstm_phase<128, false>(cg, rg, WhF, WiF, gsum, idsL, A.WhhD, A.WihD, A.embD,
                           A.desc_anchor, A.desc_neg, A.desc_anchor_len, A.desc_neg_len,
                           A.desc_bih, A.desc_bhh, hrot, nullptr, A.finals,
                           flg, TDc);
  }
}

// ---------------- attention scores via MFMA ----------------
__global__ __launch_bounds__(256) void attn_scores_mfma(
    const u16* __restrict__ featB, const u32* __restrict__ WF,
    const float* __restrict__ attn_b, const float* __restrict__ attnS_W,
    const float* __restrict__ attnS_b, float* __restrict__ scores)
{
  __shared__ __align__(16) u16 Af[4 * 16 * 64 * 8];   // 65536 B (reused as red after)
  const int tid = threadIdx.x;
  const int m0 = blockIdx.x * 64;

  #pragma unroll
  for (int i = 0; i < 16; ++i) {
    int c = (i << 8) + tid;
    int r = c >> 6, kb = c & 63;
    uint4 v = *(const uint4*)(featB + (((size_t)(m0 + r)) << 9) + (kb << 3));
    int kc = kb >> 2, lf = (r & 15) + ((kb & 3) << 4);
    *(uint4*)(Af + ((((r >> 4) * 16 + kc) << 6 | lf) << 3)) = v;
  }
  __syncthreads();

  const int w = tid >> 6, l = tid & 63;
  const u16* WF16 = (const u16*)WF;
  float p[4][4] = {};
  for (int nc = w * 4; nc < w * 4 + 4; ++nc) {
    f32x4 acc[4][2];
    #pragma unroll
    for (int rh = 0; rh < 4; ++rh) {
      acc[rh][0] = (f32x4){0.f, 0.f, 0.f, 0.f};
      acc[rh][1] = (f32x4){0.f, 0.f, 0.f, 0.f};
    }
    #pragma unroll 4
    for (int kc = 0; kc < 16; ++kc) {
      bf16x8 b0 = *(const bf16x8*)(WF16 + ((size_t)((((nc << 4) + kc) << 1 | 0) << 6 | l) << 3));
      bf16x8 b1 = *(const bf16x8*)(WF16 + ((size_t)((((nc << 4) + kc) << 1 | 1) << 6 | l) << 3));
      #pragma unroll
      for (int rh = 0; rh < 4; ++rh) {
        bf16x8 a = *(const bf16x8*)(Af + (((rh * 16 + kc) << 6 | l) << 3));
        acc[rh][0] = __builtin_amdgcn_mfma_f32_16x16x32_bf16(a, b0, acc[rh][0], 0, 0, 0);
        acc[rh][1] = __builtin_amdgcn_mfma_f32_16x16x32_bf16(a, b1, acc[rh][1], 0, 0, 0);
      }
    }
    int c0 = (nc << 5) + (l & 15), c1 = c0 + 16;
    float bb0 = attn_b[c0], sw0 = attnS_W[c0];
    float bb1 = attn_b[c1], sw1 = attnS_W[c1];
    #pragma unroll
    for (int rh = 0; rh < 4; ++rh)
      #pragma unroll
      for (int j = 0; j < 4; ++j)
        p[rh][j] += tanhf(acc[rh][0][j] + bb0) * sw0 + tanhf(acc[rh][1][j] + bb1) * sw1;
  }
  __syncthreads();
  float* red = (float*)Af;   // 64 x 68
  #pragma unroll
  for (int rh = 0; rh < 4; ++rh)
    #pragma unroll
    for (int j = 0; j < 4; ++j)
      red[(rh * 16 + ((l >> 4) << 2) + j) * 68 + (w << 4) + (l & 15)] = p[rh][j];
  __syncthreads();
  if (tid < 64) {
    float s = attnS_b[0];
    #pragma unroll 8
    for (int q = 0; q < 64; ++q) s += red[tid * 68 + q];
    scores[m0 + tid] = s;
  }
}

// masked softmax over T=200 + weighted pooling of bf16 feat -> pooled (B,H) fp32
__global__ __launch_bounds__(256) void softmax_pool_kernel(
    const float* __restrict__ scores, const int* __restrict__ tok_len,
    const u16* __restrict__ featB, float* __restrict__ pooled)
{
  const int b = blockIdx.x;
  const int tid = threadIdx.x;
  __shared__ float wgt[TCc];
  __shared__ float red[256];
  const int len = tok_len[b];

  float myv = -1e30f;
  if (tid < TCc) {
    float s = scores[b * TCc + tid];
    myv = (tid < len) ? s : -1e9f;
    wgt[tid] = myv;
  }
  red[tid] = myv;
  __syncthreads();
  for (int s = 128; s > 0; s >>= 1) {
    if (tid < s) red[tid] = fmaxf(red[tid], red[tid + s]);
    __syncthreads();
  }
  const float mx = red[0];
  __syncthreads();
  float e = 0.f;
  if (tid < TCc) e = expf(wgt[tid] - mx);
  red[tid] = e;
  __syncthreads();
  for (int s = 128; s > 0; s >>= 1) {
    if (tid < s) red[tid] += red[tid + s];
    __syncthreads();
  }
  const float sum = red[0];
  __syncthreads();
  if (tid < TCc) wgt[tid] = e / sum;
  __syncthreads();

  const u32* featU = (const u32*)featB;
  float a0 = 0.f, a1 = 0.f;
  for (int t = 0; t < TCc; ++t) {
    u32 v = featU[((size_t)b * TCc + t) * 256 + tid];
    float wv = wgt[t];
    a0 = fmaf(wv, bf2f((u16)(v & 0xFFFF)), a0);
    a1 = fmaf(wv, bf2f((u16)(v >> 16)), a1);
  }
  pooled[((size_t)b << 9) + tid * 2] = a0;
  pooled[((size_t)b << 9) + tid * 2 + 1] = a1;
}

// C[m,n] = tanh(A[m,:] . W[n,:] + bias[n]); fp32, grid (M/64, N/64)
__global__ __launch_bounds__(256) void gemm_bias_tanh_kernel(
    const float* __restrict__ A, const float* __restrict__ Bw,
    const float* __restrict__ bias, float* __restrict__ C, int M, int N, int K)
{
  const int r0 = blockIdx.x * 64;
  const int n0 = blockIdx.y * 64;
  const int tid = threadIdx.x;
  const int tu = tid & 15;
  const int tm = tid >> 4;
  __shared__ float As[32][68];
  __shared__ float Bs[32][68];

  float acc[4][4] = {};
  for (int k0 = 0; k0 < K; k0 += 32) {
    #pragma unroll
    for (int i = 0; i < 2; ++i) {
      int lin = tid + (i << 8);
      int kq = lin & 7, m = lin >> 3;
      int k = k0 + (kq << 2);
      int r = r0 + m; if (r >= M) r = M - 1;
      float4 va = *(const float4*)&A[(size_t)r * K + k];
      float4 vb = *(const float4*)&Bw[(size_t)(n0 + m) * K + k];
      As[(kq << 2) + 0][m] = va.x; As[(kq << 2) + 1][m] = va.y;
      As[(kq << 2) + 2][m] = va.z; As[(kq << 2) + 3][m] = va.w;
      Bs[(kq << 2) + 0][m] = vb.x; Bs[(kq << 2) + 1][m] = vb.y;
      Bs[(kq << 2) + 2][m] = vb.z; Bs[(kq << 2) + 3][m] = vb.w;
    }
    __syncthreads();
    #pragma unroll
    for (int kk = 0; kk < 32; ++kk) {
      float4 a = *(const float4*)&As[kk][tm << 2];
      float4 b = *(const float4*)&Bs[kk][tu << 2];
      acc[0][0] = fmaf(a.x, b.x, acc[0][0]); acc[0][1] = fmaf(a.x, b.y, acc[0][1]);
      acc[0][2] = fmaf(a.x, b.z, acc[0][2]); acc[0][3] = fmaf(a.x, b.w, acc[0][3]);
      acc[1][0] = fmaf(a.y, b.x, acc[1][0]); acc[1][1] = fmaf(a.y, b.y, acc[1][1]);
      acc[1][2] = fmaf(a.y, b.z, acc[1][2]); acc[1][3] = fmaf(a.y, b.w, acc[1][3]);
      acc[2][0] = fmaf(a.z, b.x, acc[2][0]); acc[2][1] = fmaf(a.z, b.y, acc[2][1]);
      acc[2][2] = fmaf(a.z, b.z, acc[2][2]); acc[2][3] = fmaf(a.z, b.w, acc[2][3]);
      acc[3][0] = fmaf(a.w, b.x, acc[3][0]); acc[3][1] = fmaf(a.w, b.y, acc[3][1]);
      acc[3][2] = fmaf(a.w, b.z, acc[3][2]); acc[3][3] = fmaf(a.w, b.w, acc[3][3]);
    }
    __syncthreads();
  }
  float bj[4];
  #pragma unroll
  for (int j = 0; j < 4; ++j) bj[j] = bias[n0 + (tu << 2) + j];
  #pragma unroll
  for (int i = 0; i < 4; ++i) {
    int r = r0 + (tm << 2) + i;
    if (r < M) {
      float4 v;
      v.x = tanhf(acc[i][0] + bj[0]); v.y = tanhf(acc[i][1] + bj[1]);
      v.z = tanhf(acc[i][2] + bj[2]); v.w = tanhf(acc[i][3] + bj[3]);
      *(float4*)&C[(size_t)r * N + n0 + (tu << 2)] = v;
    }
  }
}

__global__ __launch_bounds__(256) void loss_kernel(
    const float* __restrict__ code, const float* __restrict__ finals, float* __restrict__ out)
{
  const int b = threadIdx.x;
  const float* cv = code + (size_t)b * Hc;
  const float* av = finals + (size_t)b * Hc;
  const float* nv = finals + (size_t)(BATCH + b) * Hc;
  float dca = 0, dcn = 0, ncc = 0, naa = 0, nnn = 0;
  for (int k = 0; k < Hc; ++k) {
    float c = cv[k], a = av[k], n = nv[k];
    dca = fmaf(c, a, dca);
    dcn = fmaf(c, n, dcn);
    ncc = fmaf(c, c, ncc);
    naa = fmaf(a, a, naa);
    nnn = fmaf(n, n, nnn);
  }
  float cos_a = dca / fmaxf(sqrtf(ncc) * sqrtf(naa), 1e-8f);
  float cos_n = dcn / fmaxf(sqrtf(ncc) * sqrtf(nnn), 1e-8f);
  float hinge = fmaxf(0.6f - cos_a + cos_n, 1e-6f);
  __shared__ float red[256];
  red[b] = hinge;
  __syncthreads();
  for (int s = 128; s > 0; s >>= 1) {
    if (b < s) red[b] += red[b + s];
    __syncthreads();
  }
  if (b == 0) out[0] = red[0] / 256.0f;
}

extern "C" void kernel_launch(void* const* d_in, const int* in_sizes, int n_in,
                              void* d_out, int out_size, void* d_ws, size_t ws_size,
                              hipStream_t stream) {
  const int* tokens          = (const int*)d_in[0];
  const int* tok_len         = (const int*)d_in[1];
  const int* desc_anchor     = (const int*)d_in[2];
  const int* desc_anchor_len = (const int*)d_in[3];
  const int* desc_neg        = (const int*)d_in[4];
  const int* desc_neg_len    = (const int*)d_in[5];
  const float* tok_emb  = (const float*)d_in[6];
  const float* tok_Wih  = (const float*)d_in[7];
  const float* tok_Whh  = (const float*)d_in[8];
  const float* tok_bih  = (const float*)d_in[9];
  const float* tok_bhh  = (const float*)d_in[10];
  const float* desc_emb = (const float*)d_in[11];
  const float* desc_Wih = (const float*)d_in[12];
  const float* desc_Whh = (const float*)d_in[13];
  const float* desc_bih = (const float*)d_in[14];
  const float* desc_bhh = (const float*)d_in[15];
  const float* attn_W   = (const float*)d_in[16];
  const float* attn_b   = (const float*)d_in[17];
  const float* attnS_W  = (const float*)d_in[18];
  const float* attnS_b  = (const float*)d_in[19];
  const float* out_W1   = (const float*)d_in[20];
  const float* out_b1   = (const float*)d_in[21];
  const float* out_W2   = (const float*)d_in[22];
  const float* out_b2   = (const float*)d_in[23];

  float* p = (float*)d_ws;
  size_t off = 0;
  auto alloc = [&](size_t n) { float* q = p + off; off += n; return q; };

  u16*  featB  = (u16*)alloc(13107200);     // 256*200*512 bf16
  u16*  embT   = (u16*)alloc(1600000);
  u16*  embD   = (u16*)alloc(1600000);
  u32*  WihT   = (u32*)alloc(327680);
  u32*  WihD   = (u32*)alloc(327680);
  u32*  WhhT   = (u32*)alloc(524288);
  u32*  WhhD   = (u32*)alloc(524288);
  u32*  attnWF = (u32*)alloc(131072);
  u16*  hTok   = (u16*)alloc(1048576);      // 4rg x ROT16 x 32768 u16
  u16*  hDesc  = (u16*)alloc(2097152);      // 4rg x ROT16 x 65536 u16
  float* finals = alloc(262144);
  float* scores = alloc(51200);
  float* pooled = alloc(131072);
  float* a2     = alloc(131072);
  float* code   = alloc(131072);
  u32* flags = (u32*)alloc(8320);           // 8rg x 64 flags x 16 u32 + 8 claim x 16

  // weight / embedding conversions
  conv_emb_kernel<<<(VOC * (EPAD / 2) + 255) / 256, 256, 0, stream>>>(tok_emb, (u32*)embT);
  conv_emb_kernel<<<(VOC * (EPAD / 2) + 255) / 256, 256, 0, stream>>>(desc_emb, (u32*)embD);
  conv_wfrag_kernel<1><<<2048, 256, 0, stream>>>(tok_Whh, WhhT, KC_H, Hc, 524288);
  conv_wfrag_kernel<1><<<2048, 256, 0, stream>>>(desc_Whh, WhhD, KC_H, Hc, 524288);
  conv_wfrag_kernel<1><<<1280, 256, 0, stream>>>(tok_Wih, WihT, KC_E, Ec, 327680);
  conv_wfrag_kernel<1><<<1280, 256, 0, stream>>>(desc_Wih, WihD, KC_E, Ec, 327680);
  conv_wfrag_kernel<0><<<512, 256, 0, stream>>>(attn_W, attnWF, KC_H, Hc, 131072);
  zero_kernel<<<33, 256, 0, stream>>>((float*)flags, 8320);

  PArgs A;
  A.WhhT = WhhT; A.WihT = WihT; A.embT = embT;
  A.WhhD = WhhD; A.WihD = WihD; A.embD = embD;
  A.tokens = tokens; A.desc_anchor = desc_anchor; A.desc_neg = desc_neg;
  A.desc_anchor_len = desc_anchor_len; A.desc_neg_len = desc_neg_len;
  A.tok_bih = tok_bih; A.tok_bhh = tok_bhh;
  A.desc_bih = desc_bih; A.desc_bhh = desc_bhh;
  A.hTok = hTok; A.hDesc = hDesc;
  A.featB = featB; A.finals = finals; A.flags = flags;
  lstm_persist_kernel<<<512, 256, 0, stream>>>(A);

  attn_scores_mfma<<<(BATCH * TCc) / 64, 256, 0, stream>>>(
      featB, attnWF, attn_b, attnS_W, attnS_b, scores);
  softmax_pool_kernel<<<BATCH, 256, 0, stream>>>(scores, tok_len, featB, pooled);
  gemm_bias_tanh_kernel<<<dim3(BATCH / 64, Hc / 64), 256, 0, stream>>>(
      pooled, out_W1, out_b1, a2, BATCH, Hc, Hc);
  gemm_bias_tanh_kernel<<<dim3(BATCH / 64, Hc / 64), 256, 0, stream>>>(
      a2, out_W2, out_b2, code, BATCH, Hc, Hc);
  loss_kernel<<<1, 256, 0, stream>>>(code, finals, (float*)d_out);
}

// Round 15
// 1098.384 us; speedup vs baseline: 1.0876x; 1.0876x over previous
//
#include <hip/hip_runtime.h>
#include <hip/hip_bf16.h>
#include <math.h>

#define TCc 200
#define TDc 50
#define BATCH 256
#define Ec 300
#define Hc 512
#define VOC 10000
#define EPAD 320
#define KC_E 10
#define KC_H 16
#define ROT 16   // h rotation depth (L1 self-eviction window)

typedef unsigned short u16;
typedef unsigned int u32;
typedef unsigned long long u64;
typedef __bf16 bf16x8 __attribute__((ext_vector_type(8)));
typedef float f32x4 __attribute__((ext_vector_type(4)));

__device__ __forceinline__ float sigf(float x) { return 1.f / (1.f + expf(-x)); }

// fast transcendentals for the persistent kernel's critical path (rel err ~1e-6)
__device__ __forceinline__ float fsig(float x) {
  return __builtin_amdgcn_rcpf(1.f + __expf(-x));
}
__device__ __forceinline__ float ftanh(float x) {
  float e = __expf(2.f * x);
  return 1.f - 2.f * __builtin_amdgcn_rcpf(e + 1.f);
}

__device__ __forceinline__ u16 f2bf(float f) {
  unsigned u = __float_as_uint(f);
  unsigned r = (u + 0x7FFFu + ((u >> 16) & 1u)) >> 16;  // RNE
  return (u16)r;
}
__device__ __forceinline__ float bf2f(u16 v) { return __uint_as_float(((unsigned)v) << 16); }

// L2-local atomic RMW (workgroup scope)
__device__ __forceinline__ u32 l2_add(u32* p, u32 v) {
  return __hip_atomic_fetch_add(p, v, __ATOMIC_RELAXED, __HIP_MEMORY_SCOPE_WORKGROUP);
}
// sc0 = L1-bypassing, L2-served load/store; waitcnt inside asm (round-8 rule)
__device__ __forceinline__ u32 ld_l2(const u32* p) {
  u32 v;
  asm volatile("global_load_dword %0, %1, off sc0\n\ts_waitcnt vmcnt(0)"
               : "=v"(v) : "v"(p) : "memory");
  return v;
}
__device__ __forceinline__ void st_l2(u32* p, u32 v) {
  asm volatile("global_store_dword %0, %1, off sc0" :: "v"(p), "v"(v) : "memory");
}

__global__ __launch_bounds__(256) void zero_kernel(float* p, int n) {
  int i = blockIdx.x * 256 + threadIdx.x;
  if (i < n) p[i] = 0.f;
}

// emb (VOC, Ec) fp32 -> (VOC, EPAD) bf16, zero-padded
__global__ __launch_bounds__(256) void conv_emb_kernel(
    const float* __restrict__ emb, u32* __restrict__ out)
{
  int e = blockIdx.x * 256 + threadIdx.x;
  if (e >= VOC * (EPAD / 2)) return;
  int v = e / (EPAD / 2);
  int k = (e - v * (EPAD / 2)) * 2;
  float a = (k < Ec) ? emb[(size_t)v * Ec + k] : 0.f;
  float b = (k + 1 < Ec) ? emb[(size_t)v * Ec + k + 1] : 0.f;
  out[e] = (u32)f2bf(a) | ((u32)f2bf(b) << 16);
}

// Weight (rows x K) fp32 -> MFMA B-fragment order bf16 (same as round 12-14).
template<int GATES>
__global__ __launch_bounds__(256) void conv_wfrag_kernel(
    const float* __restrict__ W, u32* __restrict__ out, int KC, int KREAL, int total)
{
  int e = blockIdx.x * 256 + threadIdx.x;
  if (e >= total) return;
  int jp = e & 3;
  int l = (e >> 2) & 63;
  int si = (e >> 8) & 1;
  int t2 = e >> 9;
  int kc = t2 % KC;
  int nc = t2 / KC;
  int c32 = (si << 4) + (l & 15);
  int srow;
  if (GATES) {
    int ulp = c32 >> 2, g = c32 & 3;
    int unit = ((ulp & 3) << 1) | (ulp >> 2);
    srow = (g << 9) + nc * 8 + unit;
  } else {
    srow = nc * 32 + c32;
  }
  int k = (kc << 5) + ((l >> 4) << 3) + (jp << 1);
  float a = (k < KREAL) ? W[(size_t)srow * KREAL + k] : 0.f;
  float b = (k + 1 < KREAL) ? W[(size_t)srow * KREAL + k + 1] : 0.f;
  out[e] = (u32)f2bf(a) | ((u32)f2bf(b) << 16);
}

// ---------------- persistent MFMA LSTM, XCD-local rowgroups ----------------
// Barrier: flag array in XCD L2 (sc0). KEY (round 15): wave 0 NEVER issues a slow
// global store — feat stores are handed to waves 1-3 via LDS, so wave 0's poll
// (vmcnt FIFO drain) never stalls on HBM write-allocate acks.
__device__ __forceinline__ void bar_signal(u32* flg, int cg, u32 gen) {
  asm volatile("s_waitcnt vmcnt(0)" ::: "memory");   // h stores acked by L2
  __syncthreads();
  if (threadIdx.x == 0) st_l2(flg + (cg << 4), gen);
}
__device__ __forceinline__ void bar_wait(u32* flg, u32 gen) {
  if (threadIdx.x < 64) {
    for (;;) {
      u32 v = ld_l2(flg + ((int)threadIdx.x << 4));
      if (__all(v >= gen)) break;
      __builtin_amdgcn_s_sleep(1);
    }
  }
  __syncthreads();
}

struct PArgs {
  const u32* WhhT; const u32* WihT; const u16* embT;
  const u32* WhhD; const u32* WihD; const u16* embD;
  const int* tokens; const int* desc_anchor; const int* desc_neg;
  const int* desc_anchor_len; const int* desc_neg_len;
  const float* tok_bih; const float* tok_bhh;
  const float* desc_bih; const float* desc_bhh;
  u16* hTok; u16* hDesc;
  u16* featB; float* finals;
  u32* flags;
};

// cg in [0,64); rg fixed by XCD. ROWS=64 (tok) / 128 (desc). RPW = ROWS/64.
template<int ROWS, bool IS_TOK>
__device__ void lstm_phase(
    int cg, int rg, u16* WhF, u16* WiF, float* gsum, int* idsL, u32* featS,
    const u32* __restrict__ WhhF, const u32* __restrict__ WihF, const u16* __restrict__ embB,
    const int* __restrict__ idsA, const int* __restrict__ idsB,
    const int* __restrict__ lenA, const int* __restrict__ lenB,
    const float* __restrict__ bih, const float* __restrict__ bhh,
    u16* __restrict__ hrot,
    u16* __restrict__ featB, float* __restrict__ finals,
    u32* flg, int T)
{
  constexpr int RPW = ROWS / 64;
  constexpr size_t BUFN = (size_t)ROWS << 9;
  const int tid = threadIdx.x;
  const int row0 = rg * ROWS;
  const int w = tid >> 6, l = tid & 63;
  const int rl = tid >> 2, u = tid & 3;
  u32 gen = 0;

  // stage weight fragments into LDS
  {
    const uint4* s = (const uint4*)(WhhF + ((size_t)cg << 13));
    uint4* d = (uint4*)WhF;
    #pragma unroll
    for (int i = 0; i < 8; ++i) d[(i << 8) + tid] = s[(i << 8) + tid];
    const uint4* s2 = (const uint4*)(WihF + (size_t)cg * 5120);
    uint4* d2 = (uint4*)WiF;
    #pragma unroll
    for (int i = 0; i < 5; ++i) d2[(i << 8) + tid] = s2[(i << 8) + tid];
  }

  const int ug0 = (cg << 3) + (u << 1);
  float bsv[2][4];
  #pragma unroll
  for (int uu = 0; uu < 2; ++uu)
    #pragma unroll
    for (int g = 0; g < 4; ++g)
      bsv[uu][g] = bih[(g << 9) + ug0 + uu] + bhh[(g << 9) + ug0 + uu];

  const int kcs    = ug0 >> 5;
  const int lanehi = (ug0 >> 3) & 3;
  const int jpos   = ug0 & 7;

  float cc[RPW][2];
  int lens[RPW];
  #pragma unroll
  for (int p = 0; p < RPW; ++p) {
    cc[p][0] = 0.f; cc[p][1] = 0.f;
    int lrow = (p << 6) + rl;
    int row = row0 + lrow;
    lens[p] = IS_TOK ? 0 : ((row < BATCH) ? lenA[row] : lenB[row - BATCH]);
    int rhp = lrow >> 4;
    int lane_s = (rl & 15) | (lanehi << 4);
    size_t off16 = ((((size_t)rhp << 4) + kcs) << 6 | lane_s) << 3 | jpos;
    *(u32*)(hrot + off16) = 0u;
  }
  ++gen; bar_signal(flg, cg, gen);

  for (int t = 0; t < T; ++t) {
    const u16* hin = hrot + (size_t)(t & (ROT - 1)) * BUFN;
    u16* hout = hrot + (size_t)((t + 1) & (ROT - 1)) * BUFN;

    if (tid < ROWS) {
      int row = row0 + tid;
      idsL[tid] = IS_TOK ? idsA[row * T + t]
                         : ((row < BATCH) ? idsA[row * T + t] : idsB[(row - BATCH) * T + t]);
    }
    __syncthreads();

    f32x4 acc[RPW][2];
    #pragma unroll
    for (int p = 0; p < RPW; ++p) {
      acc[p][0] = (f32x4){0.f, 0.f, 0.f, 0.f};
      acc[p][1] = (f32x4){0.f, 0.f, 0.f, 0.f};
    }
    const u16* eb[RPW];
    const u16* hfb[RPW];
    #pragma unroll
    for (int p = 0; p < RPW; ++p) {
      int rhp = w + (p << 2);
      int ida = idsL[(rhp << 4) + (l & 15)];
      eb[p] = embB + (size_t)ida * EPAD + ((l >> 4) << 3);
      hfb[p] = hin + ((((size_t)rhp << 4) << 9) | (l << 3));
    }

    // ---- h-independent input-projection MFMAs first ----
    #pragma unroll
    for (int kc = 0; kc < KC_E; ++kc) {
      bf16x8 b0 = *(const bf16x8*)(WiF + ((((kc << 1) | 0) << 6 | l) << 3));
      bf16x8 b1 = *(const bf16x8*)(WiF + ((((kc << 1) | 1) << 6 | l) << 3));
      #pragma unroll
      for (int p = 0; p < RPW; ++p) {
        bf16x8 a = *(const bf16x8*)(eb[p] + (kc << 5));
        acc[p][0] = __builtin_amdgcn_mfma_f32_16x16x32_bf16(a, b0, acc[p][0], 0, 0, 0);
        acc[p][1] = __builtin_amdgcn_mfma_f32_16x16x32_bf16(a, b1, acc[p][1], 0, 0, 0);
      }
    }

    // ---- wait for h(t-1) (wave0's vmem FIFO is clean: no slow stores issued) ----
    bar_wait(flg, gen);

    // ---- recurrent MFMAs from plain cached 16B loads (XCD-L2 hits) ----
    #pragma unroll
    for (int kc = 0; kc < KC_H; ++kc) {
      bf16x8 b0 = *(const bf16x8*)(WhF + ((((kc << 1) | 0) << 6 | l) << 3));
      bf16x8 b1 = *(const bf16x8*)(WhF + ((((kc << 1) | 1) << 6 | l) << 3));
      #pragma unroll
      for (int p = 0; p < RPW; ++p) {
        bf16x8 a = *(const bf16x8*)(hfb[p] + (kc << 9));
        acc[p][0] = __builtin_amdgcn_mfma_f32_16x16x32_bf16(a, b0, acc[p][0], 0, 0, 0);
        acc[p][1] = __builtin_amdgcn_mfma_f32_16x16x32_bf16(a, b1, acc[p][1], 0, 0, 0);
      }
    }

    // ---- epilogue: gates, c/h update; h store (L2-fast); feat -> LDS only ----
    #pragma unroll
    for (int p = 0; p < RPW; ++p) {
      int lr0 = (w << 4) + ((l >> 4) << 2);
      #pragma unroll
      for (int si = 0; si < 2; ++si)
        #pragma unroll
        for (int j = 0; j < 4; ++j)
          gsum[(lr0 + j) * 36 + (si << 4) + (l & 15)] = acc[p][si][j];
      __syncthreads();
      {
        float4 g0 = *(const float4*)&gsum[rl * 36 + (u << 2)];
        float4 g1 = *(const float4*)&gsum[rl * 36 + ((u + 4) << 2)];
        int lrow = (p << 6) + rl;
        int row = row0 + lrow;
        float gi0 = fsig(g0.x + bsv[0][0]);
        float gf0 = fsig(g0.y + bsv[0][1]);
        float gg0 = ftanh(g0.z + bsv[0][2]);
        float go0 = fsig(g0.w + bsv[0][3]);
        float cn0 = gf0 * cc[p][0] + gi0 * gg0;
        cc[p][0] = cn0;
        float hn0 = go0 * ftanh(cn0);
        float gi1 = fsig(g1.x + bsv[1][0]);
        float gf1 = fsig(g1.y + bsv[1][1]);
        float gg1 = ftanh(g1.z + bsv[1][2]);
        float go1 = fsig(g1.w + bsv[1][3]);
        float cn1 = gf1 * cc[p][1] + gi1 * gg1;
        cc[p][1] = cn1;
        float hn1 = go1 * ftanh(cn1);
        int rhp = lrow >> 4;
        int lane_s = (rl & 15) | (lanehi << 4);
        size_t off16 = ((((size_t)rhp << 4) + kcs) << 6 | lane_s) << 3 | jpos;
        *(u32*)(hout + off16) = (u32)f2bf(hn0) | ((u32)f2bf(hn1) << 16);
        if constexpr (IS_TOK) {
          featS[tid] = (u32)f2bf(ftanh(hn0)) | ((u32)f2bf(ftanh(hn1)) << 16);
        } else {
          if (t == lens[p] - 1) {
            finals[((size_t)row << 9) + ug0]     = ftanh(hn0);
            finals[((size_t)row << 9) + ug0 + 1] = ftanh(hn1);
          }
        }
      }
      __syncthreads();
    }
    ++gen; bar_signal(flg, cg, gen);   // vmcnt0 here drains only fast L2 h-stores

    if constexpr (IS_TOK) {
      // feat global stores by waves 1-3 ONLY (wave 0 stays store-free for its poll).
      // featS ordering guaranteed by bar_signal's __syncthreads.
      if (tid >= 64) {
        for (int s = tid - 64; s < 256; s += 192) {
          int row = row0 + (s >> 2);
          int sug = (cg << 3) + ((s & 3) << 1);
          size_t fo = ((size_t)row * TCc + t) << 9;
          *(u32*)(featB + fo + sug) = featS[s];
        }
      }
    }
  }
}

// 512 blocks; each claims (xcd, rank). 2 blocks/CU -> exactly 64 blocks/XCD.
__global__ void __launch_bounds__(256, 1) lstm_persist_kernel(PArgs A) {
  __shared__ __align__(16) u16 WhF[KC_H * 2 * 64 * 8];   // 32768 B
  __shared__ __align__(16) u16 WiF[KC_E * 2 * 64 * 8];   // 20480 B
  __shared__ __align__(16) float gsum[64 * 36];          // 9216 B
  __shared__ int idsL[128];                              // 512 B
  __shared__ u32 featS[256];                             // 1024 B
  __shared__ int s_claim[2];
  if (threadIdx.x == 0) {
    int xcd;
    asm("s_getreg_b32 %0, hwreg(HW_REG_XCC_ID)" : "=s"(xcd));
    xcd &= 7;
    u32 rank = l2_add(A.flags + 8192 + (xcd << 4), 1u);
    s_claim[0] = xcd;
    s_claim[1] = (int)rank;
  }
  __syncthreads();
  const int xcd = s_claim[0];
  const int cg = s_claim[1] & 63;

  if (xcd < 4) {
    int rg = xcd;
    u32* flg = A.flags + (rg << 10);
    u16* hrot = A.hTok + (size_t)rg * ROT * ((size_t)64 << 9);
    lstm_phase<64, true>(cg, rg, WhF, WiF, gsum, idsL, featS, A.WhhT, A.WihT, A.embT,
                         A.tokens, nullptr, nullptr, nullptr,
                         A.tok_bih, A.tok_bhh, hrot, A.featB, nullptr,
                         flg, TCc);
  } else {
    int rg = xcd - 4;
    u32* flg = A.flags + ((4 + rg) << 10);
    u16* hrot = A.hDesc + (size_t)rg * ROT * ((size_t)128 << 9);
    lstm_phase<128, false>(cg, rg, WhF, WiF, gsum, idsL, featS, A.WhhD, A.WihD, A.embD,
                           A.desc_anchor, A.desc_neg, A.desc_anchor_len, A.desc_neg_len,
                           A.desc_bih, A.desc_bhh, hrot, nullptr, A.finals,
                           flg, TDc);
  }
}

// ---------------- attention scores via MFMA ----------------
__global__ __launch_bounds__(256) void attn_scores_mfma(
    const u16* __restrict__ featB, const u32* __restrict__ WF,
    const float* __restrict__ attn_b, const float* __restrict__ attnS_W,
    const float* __restrict__ attnS_b, float* __restrict__ scores)
{
  __shared__ __align__(16) u16 Af[4 * 16 * 64 * 8];   // 65536 B
  const int tid = threadIdx.x;
  const int m0 = blockIdx.x * 64;

  #pragma unroll
  for (int i = 0; i < 16; ++i) {
    int c = (i << 8) + tid;
    int r = c >> 6, kb = c & 63;
    uint4 v = *(const uint4*)(featB + (((size_t)(m0 + r)) << 9) + (kb << 3));
    int kc = kb >> 2, lf = (r & 15) + ((kb & 3) << 4);
    *(uint4*)(Af + ((((r >> 4) * 16 + kc) << 6 | lf) << 3)) = v;
  }
  __syncthreads();

  const int w = tid >> 6, l = tid & 63;
  const u16* WF16 = (const u16*)WF;
  float p[4][4] = {};
  for (int nc = w * 4; nc < w * 4 + 4; ++nc) {
    f32x4 acc[4][2];
    #pragma unroll
    for (int rh = 0; rh < 4; ++rh) {
      acc[rh][0] = (f32x4){0.f, 0.f, 0.f, 0.f};
      acc[rh][1] = (f32x4){0.f, 0.f, 0.f, 0.f};
    }
    #pragma unroll 4
    for (int kc = 0; kc < 16; ++kc) {
      bf16x8 b0 = *(const bf16x8*)(WF16 + ((size_t)((((nc << 4) + kc) << 1 | 0) << 6 | l) << 3));
      bf16x8 b1 = *(const bf16x8*)(WF16 + ((size_t)((((nc << 4) + kc) << 1 | 1) << 6 | l) << 3));
      #pragma unroll
      for (int rh = 0; rh < 4; ++rh) {
        bf16x8 a = *(const bf16x8*)(Af + (((rh * 16 + kc) << 6 | l) << 3));
        acc[rh][0] = __builtin_amdgcn_mfma_f32_16x16x32_bf16(a, b0, acc[rh][0], 0, 0, 0);
        acc[rh][1] = __builtin_amdgcn_mfma_f32_16x16x32_bf16(a, b1, acc[rh][1], 0, 0, 0);
      }
    }
    int c0 = (nc << 5) + (l & 15), c1 = c0 + 16;
    float bb0 = attn_b[c0], sw0 = attnS_W[c0];
    float bb1 = attn_b[c1], sw1 = attnS_W[c1];
    #pragma unroll
    for (int rh = 0; rh < 4; ++rh)
      #pragma unroll
      for (int j = 0; j < 4; ++j)
        p[rh][j] += tanhf(acc[rh][0][j] + bb0) * sw0 + tanhf(acc[rh][1][j] + bb1) * sw1;
  }
  __syncthreads();
  float* red = (float*)Af;   // 64 x 68
  #pragma unroll
  for (int rh = 0; rh < 4; ++rh)
    #pragma unroll
    for (int j = 0; j < 4; ++j)
      red[(rh * 16 + ((l >> 4) << 2) + j) * 68 + (w << 4) + (l & 15)] = p[rh][j];
  __syncthreads();
  if (tid < 64) {
    float s = attnS_b[0];
    #pragma unroll 8
    for (int q = 0; q < 64; ++q) s += red[tid * 68 + q];
    scores[m0 + tid] = s;
  }
}

// masked softmax over T=200 + weighted pooling of bf16 feat -> pooled (B,H) fp32
__global__ __launch_bounds__(256) void softmax_pool_kernel(
    const float* __restrict__ scores, const int* __restrict__ tok_len,
    const u16* __restrict__ featB, float* __restrict__ pooled)
{
  const int b = blockIdx.x;
  const int tid = threadIdx.x;
  __shared__ float wgt[TCc];
  __shared__ float red[256];
  const int len = tok_len[b];

  float myv = -1e30f;
  if (tid < TCc) {
    float s = scores[b * TCc + tid];
    myv = (tid < len) ? s : -1e9f;
    wgt[tid] = myv;
  }
  red[tid] = myv;
  __syncthreads();
  for (int s = 128; s > 0; s >>= 1) {
    if (tid < s) red[tid] = fmaxf(red[tid], red[tid + s]);
    __syncthreads();
  }
  const float mx = red[0];
  __syncthreads();
  float e = 0.f;
  if (tid < TCc) e = expf(wgt[tid] - mx);
  red[tid] = e;
  __syncthreads();
  for (int s = 128; s > 0; s >>= 1) {
    if (tid < s) red[tid] += red[tid + s];
    __syncthreads();
  }
  const float sum = red[0];
  __syncthreads();
  if (tid < TCc) wgt[tid] = e / sum;
  __syncthreads();

  const u32* featU = (const u32*)featB;
  float a0 = 0.f, a1 = 0.f;
  for (int t = 0; t < TCc; ++t) {
    u32 v = featU[((size_t)b * TCc + t) * 256 + tid];
    float wv = wgt[t];
    a0 = fmaf(wv, bf2f((u16)(v & 0xFFFF)), a0);
    a1 = fmaf(wv, bf2f((u16)(v >> 16)), a1);
  }
  pooled[((size_t)b << 9) + tid * 2] = a0;
  pooled[((size_t)b << 9) + tid * 2 + 1] = a1;
}

// C[m,n] = tanh(A[m,:] . W[n,:] + bias[n]); fp32, grid (M/64, N/64)
__global__ __launch_bounds__(256) void gemm_bias_tanh_kernel(
    const float* __restrict__ A, const float* __restrict__ Bw,
    const float* __restrict__ bias, float* __restrict__ C, int M, int N, int K)
{
  const int r0 = blockIdx.x * 64;
  const int n0 = blockIdx.y * 64;
  const int tid = threadIdx.x;
  const int tu = tid & 15;
  const int tm = tid >> 4;
  __shared__ float As[32][68];
  __shared__ float Bs[32][68];

  float acc[4][4] = {};
  for (int k0 = 0; k0 < K; k0 += 32) {
    #pragma unroll
    for (int i = 0; i < 2; ++i) {
      int lin = tid + (i << 8);
      int kq = lin & 7, m = lin >> 3;
      int k = k0 + (kq << 2);
      int r = r0 + m; if (r >= M) r = M - 1;
      float4 va = *(const float4*)&A[(size_t)r * K + k];
      float4 vb = *(const float4*)&Bw[(size_t)(n0 + m) * K + k];
      As[(kq << 2) + 0][m] = va.x; As[(kq << 2) + 1][m] = va.y;
      As[(kq << 2) + 2][m] = va.z; As[(kq << 2) + 3][m] = va.w;
      Bs[(kq << 2) + 0][m] = vb.x; Bs[(kq << 2) + 1][m] = vb.y;
      Bs[(kq << 2) + 2][m] = vb.z; Bs[(kq << 2) + 3][m] = vb.w;
    }
    __syncthreads();
    #pragma unroll
    for (int kk = 0; kk < 32; ++kk) {
      float4 a = *(const float4*)&As[kk][tm << 2];
      float4 b = *(const float4*)&Bs[kk][tu << 2];
      acc[0][0] = fmaf(a.x, b.x, acc[0][0]); acc[0][1] = fmaf(a.x, b.y, acc[0][1]);
      acc[0][2] = fmaf(a.x, b.z, acc[0][2]); acc[0][3] = fmaf(a.x, b.w, acc[0][3]);
      acc[1][0] = fmaf(a.y, b.x, acc[1][0]); acc[1][1] = fmaf(a.y, b.y, acc[1][1]);
      acc[1][2] = fmaf(a.y, b.z, acc[1][2]); acc[1][3] = fmaf(a.y, b.w, acc[1][3]);
      acc[2][0] = fmaf(a.z, b.x, acc[2][0]); acc[2][1] = fmaf(a.z, b.y, acc[2][1]);
      acc[2][2] = fmaf(a.z, b.z, acc[2][2]); acc[2][3] = fmaf(a.z, b.w, acc[2][3]);
      acc[3][0] = fmaf(a.w, b.x, acc[3][0]); acc[3][1] = fmaf(a.w, b.y, acc[3][1]);
      acc[3][2] = fmaf(a.w, b.z, acc[3][2]); acc[3][3] = fmaf(a.w, b.w, acc[3][3]);
    }
    __syncthreads();
  }
  float bj[4];
  #pragma unroll
  for (int j = 0; j < 4; ++j) bj[j] = bias[n0 + (tu << 2) + j];
  #pragma unroll
  for (int i = 0; i < 4; ++i) {
    int r = r0 + (tm << 2) + i;
    if (r < M) {
      float4 v;
      v.x = tanhf(acc[i][0] + bj[0]); v.y = tanhf(acc[i][1] + bj[1]);
      v.z = tanhf(acc[i][2] + bj[2]); v.w = tanhf(acc[i][3] + bj[3]);
      *(float4*)&C[(size_t)r * N + n0 + (tu << 2)] = v;
    }
  }
}

__global__ __launch_bounds__(256) void loss_kernel(
    const float* __restrict__ code, const float* __restrict__ finals, float* __restrict__ out)
{
  const int b = threadIdx.x;
  const float* cv = code + (size_t)b * Hc;
  const float* av = finals + (size_t)b * Hc;
  const float* nv = finals + (size_t)(BATCH + b) * Hc;
  float dca = 0, dcn = 0, ncc = 0, naa = 0, nnn = 0;
  for (int k = 0; k < Hc; ++k) {
    float c = cv[k], a = av[k], n = nv[k];
    dca = fmaf(c, a, dca);
    dcn = fmaf(c, n, dcn);
    ncc = fmaf(c, c, ncc);
    naa = fmaf(a, a, naa);
    nnn = fmaf(n, n, nnn);
  }
  float cos_a = dca / fmaxf(sqrtf(ncc) * sqrtf(naa), 1e-8f);
  float cos_n = dcn / fmaxf(sqrtf(ncc) * sqrtf(nnn), 1e-8f);
  float hinge = fmaxf(0.6f - cos_a + cos_n, 1e-6f);
  __shared__ float red[256];
  red[b] = hinge;
  __syncthreads();
  for (int s = 128; s > 0; s >>= 1) {
    if (b < s) red[b] += red[b + s];
    __syncthreads();
  }
  if (b == 0) out[0] = red[0] / 256.0f;
}

extern "C" void kernel_launch(void* const* d_in, const int* in_sizes, int n_in,
                              void* d_out, int out_size, void* d_ws, size_t ws_size,
                              hipStream_t stream) {
  const int* tokens          = (const int*)d_in[0];
  const int* tok_len         = (const int*)d_in[1];
  const int* desc_anchor     = (const int*)d_in[2];
  const int* desc_anchor_len = (const int*)d_in[3];
  const int* desc_neg        = (const int*)d_in[4];
  const int* desc_neg_len    = (const int*)d_in[5];
  const float* tok_emb  = (const float*)d_in[6];
  const float* tok_Wih  = (const float*)d_in[7];
  const float* tok_Whh  = (const float*)d_in[8];
  const float* tok_bih  = (const float*)d_in[9];
  const float* tok_bhh  = (const float*)d_in[10];
  const float* desc_emb = (const float*)d_in[11];
  const float* desc_Wih = (const float*)d_in[12];
  const float* desc_Whh = (const float*)d_in[13];
  const float* desc_bih = (const float*)d_in[14];
  const float* desc_bhh = (const float*)d_in[15];
  const float* attn_W   = (const float*)d_in[16];
  const float* attn_b   = (const float*)d_in[17];
  const float* attnS_W  = (const float*)d_in[18];
  const float* attnS_b  = (const float*)d_in[19];
  const float* out_W1   = (const float*)d_in[20];
  const float* out_b1   = (const float*)d_in[21];
  const float* out_W2   = (const float*)d_in[22];
  const float* out_b2   = (const float*)d_in[23];

  float* p = (float*)d_ws;
  size_t off = 0;
  auto alloc = [&](size_t n) { float* q = p + off; off += n; return q; };

  u16*  featB  = (u16*)alloc(13107200);
  u16*  embT   = (u16*)alloc(1600000);
  u16*  embD   = (u16*)alloc(1600000);
  u32*  WihT   = (u32*)alloc(327680);
  u32*  WihD   = (u32*)alloc(327680);
  u32*  WhhT   = (u32*)alloc(524288);
  u32*  WhhD   = (u32*)alloc(524288);
  u32*  attnWF = (u32*)alloc(131072);
  u16*  hTok   = (u16*)alloc(1048576);
  u16*  hDesc  = (u16*)alloc(2097152);
  float* finals = alloc(262144);
  float* scores = alloc(51200);
  float* pooled = alloc(131072);
  float* a2     = alloc(131072);
  float* code   = alloc(131072);
  u32* flags = (u32*)alloc(8320);

  conv_emb_kernel<<<(VOC * (EPAD / 2) + 255) / 256, 256, 0, stream>>>(tok_emb, (u32*)embT);
  conv_emb_kernel<<<(VOC * (EPAD / 2) + 255) / 256, 256, 0, stream>>>(desc_emb, (u32*)embD);
  conv_wfrag_kernel<1><<<2048, 256, 0, stream>>>(tok_Whh, WhhT, KC_H, Hc, 524288);
  conv_wfrag_kernel<1><<<2048, 256, 0, stream>>>(desc_Whh, WhhD, KC_H, Hc, 524288);
  conv_wfrag_kernel<1><<<1280, 256, 0, stream>>>(tok_Wih, WihT, KC_E, Ec, 327680);
  conv_wfrag_kernel<1><<<1280, 256, 0, stream>>>(desc_Wih, WihD, KC_E, Ec, 327680);
  conv_wfrag_kernel<0><<<512, 256, 0, stream>>>(attn_W, attnWF, KC_H, Hc, 131072);
  zero_kernel<<<33, 256, 0, stream>>>((float*)flags, 8320);

  PArgs A;
  A.WhhT = WhhT; A.WihT = WihT; A.embT = embT;
  A.WhhD = WhhD; A.WihD = WihD; A.embD = embD;
  A.tokens = tokens; A.desc_anchor = desc_anchor; A.desc_neg = desc_neg;
  A.desc_anchor_len = desc_anchor_len; A.desc_neg_len = desc_neg_len;
  A.tok_bih = tok_bih; A.tok_bhh = tok_bhh;
  A.desc_bih = desc_bih; A.desc_bhh = desc_bhh;
  A.hTok = hTok; A.hDesc = hDesc;
  A.featB = featB; A.finals = finals; A.flags = flags;
  lstm_persist_kernel<<<512, 256, 0, stream>>>(A);

  attn_scores_mfma<<<(BATCH * TCc) / 64, 256, 0, stream>>>(
      featB, attnWF, attn_b, attnS_W, attnS_b, scores);
  softmax_pool_kernel<<<BATCH, 256, 0, stream>>>(scores, tok_len, featB, pooled);
  gemm_bias_tanh_kernel<<<dim3(BATCH / 64, Hc / 64), 256, 0, stream>>>(
      pooled, out_W1, out_b1, a2, BATCH, Hc, Hc);
  gemm_bias_tanh_kernel<<<dim3(BATCH / 64, Hc / 64), 256, 0, stream>>>(
      a2, out_W2, out_b2, code, BATCH, Hc, Hc);
  loss_kernel<<<1, 256, 0, stream>>>(code, finals, (float*)d_out);
}

// Round 18
// 1095.700 us; speedup vs baseline: 1.0903x; 1.0024x over previous
//
#include <hip/hip_runtime.h>
#include <hip/hip_bf16.h>
#include <math.h>

#define TCc 200
#define TDc 50
#define BATCH 256
#define Ec 300
#define Hc 512
#define VOC 10000
#define EPAD 320
#define KC_E 10
#define KC_H 16
#define ROT 16   // h rotation depth (L1 self-eviction window)

typedef unsigned short u16;
typedef unsigned int u32;
typedef unsigned long long u64;
typedef __bf16 bf16x8 __attribute__((ext_vector_type(8)));
typedef float f32x4 __attribute__((ext_vector_type(4)));

__device__ __forceinline__ float sigf(float x) { return 1.f / (1.f + expf(-x)); }

// fast transcendentals (rel err ~1e-6, far below bf16 rounding)
__device__ __forceinline__ float fsig(float x) {
  return __builtin_amdgcn_rcpf(1.f + __expf(-x));
}
__device__ __forceinline__ float ftanh(float x) {
  float e = __expf(2.f * x);
  return 1.f - 2.f * __builtin_amdgcn_rcpf(e + 1.f);
}

__device__ __forceinline__ u16 f2bf(float f) {
  unsigned u = __float_as_uint(f);
  unsigned r = (u + 0x7FFFu + ((u >> 16) & 1u)) >> 16;  // RNE
  return (u16)r;
}
__device__ __forceinline__ float bf2f(u16 v) { return __uint_as_float(((unsigned)v) << 16); }

// L2-local atomic RMW (workgroup scope)
__device__ __forceinline__ u32 l2_add(u32* p, u32 v) {
  return __hip_atomic_fetch_add(p, v, __ATOMIC_RELAXED, __HIP_MEMORY_SCOPE_WORKGROUP);
}
// sc0 = L1-bypassing, L2-served load/store; waitcnt inside asm (round-8 rule)
__device__ __forceinline__ u32 ld_l2(const u32* p) {
  u32 v;
  asm volatile("global_load_dword %0, %1, off sc0\n\ts_waitcnt vmcnt(0)"
               : "=v"(v) : "v"(p) : "memory");
  return v;
}
__device__ __forceinline__ void st_l2(u32* p, u32 v) {
  asm volatile("global_store_dword %0, %1, off sc0" :: "v"(p), "v"(v) : "memory");
}

__global__ __launch_bounds__(256) void zero_kernel(float* p, int n) {
  int i = blockIdx.x * 256 + threadIdx.x;
  if (i < n) p[i] = 0.f;
}

// emb (VOC, Ec) fp32 -> (VOC, EPAD) bf16, zero-padded
__global__ __launch_bounds__(256) void conv_emb_kernel(
    const float* __restrict__ emb, u32* __restrict__ out)
{
  int e = blockIdx.x * 256 + threadIdx.x;
  if (e >= VOC * (EPAD / 2)) return;
  int v = e / (EPAD / 2);
  int k = (e - v * (EPAD / 2)) * 2;
  float a = (k < Ec) ? emb[(size_t)v * Ec + k] : 0.f;
  float b = (k + 1 < Ec) ? emb[(size_t)v * Ec + k + 1] : 0.f;
  out[e] = (u32)f2bf(a) | ((u32)f2bf(b) << 16);
}

// Weight (rows x K) fp32 -> MFMA B-fragment order bf16 (same as rounds 12-15).
template<int GATES>
__global__ __launch_bounds__(256) void conv_wfrag_kernel(
    const float* __restrict__ W, u32* __restrict__ out, int KC, int KREAL, int total)
{
  int e = blockIdx.x * 256 + threadIdx.x;
  if (e >= total) return;
  int jp = e & 3;
  int l = (e >> 2) & 63;
  int si = (e >> 8) & 1;
  int t2 = e >> 9;
  int kc = t2 % KC;
  int nc = t2 / KC;
  int c32 = (si << 4) + (l & 15);
  int srow;
  if (GATES) {
    int ulp = c32 >> 2, g = c32 & 3;
    int unit = ((ulp & 3) << 1) | (ulp >> 2);
    srow = (g << 9) + nc * 8 + unit;
  } else {
    srow = nc * 32 + c32;
  }
  int k = (kc << 5) + ((l >> 4) << 3) + (jp << 1);
  float a = (k < KREAL) ? W[(size_t)srow * KREAL + k] : 0.f;
  float b = (k + 1 < KREAL) ? W[(size_t)srow * KREAL + k + 1] : 0.f;
  out[e] = (u32)f2bf(a) | ((u32)f2bf(b) << 16);
}

// ---------------- persistent MFMA LSTM, XCD-local rowgroups ----------------
// (round-15 structure, verbatim: known-good. Rounds 16/17's emb prefetch +
// ids double-buffer deadlocked twice -> abandoned.)
__device__ __forceinline__ void bar_signal(u32* flg, int cg, u32 gen) {
  asm volatile("s_waitcnt vmcnt(0)" ::: "memory");
  __syncthreads();
  if (threadIdx.x == 0) st_l2(flg + (cg << 4), gen);
}
__device__ __forceinline__ void bar_wait(u32* flg, u32 gen) {
  if (threadIdx.x < 64) {
    for (;;) {
      u32 v = ld_l2(flg + ((int)threadIdx.x << 4));
      if (__all(v >= gen)) break;
      __builtin_amdgcn_s_sleep(1);
    }
  }
  __syncthreads();
}

struct PArgs {
  const u32* WhhT; const u32* WihT; const u16* embT;
  const u32* WhhD; const u32* WihD; const u16* embD;
  const int* tokens; const int* desc_anchor; const int* desc_neg;
  const int* desc_anchor_len; const int* desc_neg_len;
  const float* tok_bih; const float* tok_bhh;
  const float* desc_bih; const float* desc_bhh;
  u16* hTok; u16* hDesc;
  u16* featB; float* finals;
  u32* flags;
};

// cg in [0,64); rg fixed by XCD. ROWS=64 (tok) / 128 (desc). RPW = ROWS/64.
template<int ROWS, bool IS_TOK>
__device__ void lstm_phase(
    int cg, int rg, u16* WhF, u16* WiF, float* gsum, int* idsL, u32* featS,
    const u32* __restrict__ WhhF, const u32* __restrict__ WihF, const u16* __restrict__ embB,
    const int* __restrict__ idsA, const int* __restrict__ idsB,
    const int* __restrict__ lenA, const int* __restrict__ lenB,
    const float* __restrict__ bih, const float* __restrict__ bhh,
    u16* __restrict__ hrot,
    u16* __restrict__ featB, float* __restrict__ finals,
    u32* flg, int T)
{
  constexpr int RPW = ROWS / 64;
  constexpr size_t BUFN = (size_t)ROWS << 9;
  const int tid = threadIdx.x;
  const int row0 = rg * ROWS;
  const int w = tid >> 6, l = tid & 63;
  const int rl = tid >> 2, u = tid & 3;
  u32 gen = 0;

  // stage weight fragments into LDS
  {
    const uint4* s = (const uint4*)(WhhF + ((size_t)cg << 13));
    uint4* d = (uint4*)WhF;
    #pragma unroll
    for (int i = 0; i < 8; ++i) d[(i << 8) + tid] = s[(i << 8) + tid];
    const uint4* s2 = (const uint4*)(WihF + (size_t)cg * 5120);
    uint4* d2 = (uint4*)WiF;
    #pragma unroll
    for (int i = 0; i < 5; ++i) d2[(i << 8) + tid] = s2[(i << 8) + tid];
  }

  const int ug0 = (cg << 3) + (u << 1);
  float bsv[2][4];
  #pragma unroll
  for (int uu = 0; uu < 2; ++uu)
    #pragma unroll
    for (int g = 0; g < 4; ++g)
      bsv[uu][g] = bih[(g << 9) + ug0 + uu] + bhh[(g << 9) + ug0 + uu];

  const int kcs    = ug0 >> 5;
  const int lanehi = (ug0 >> 3) & 3;
  const int jpos   = ug0 & 7;

  float cc[RPW][2];
  int lens[RPW];
  #pragma unroll
  for (int p = 0; p < RPW; ++p) {
    cc[p][0] = 0.f; cc[p][1] = 0.f;
    int lrow = (p << 6) + rl;
    int row = row0 + lrow;
    lens[p] = IS_TOK ? 0 : ((row < BATCH) ? lenA[row] : lenB[row - BATCH]);
    int rhp = lrow >> 4;
    int lane_s = (rl & 15) | (lanehi << 4);
    size_t off16 = ((((size_t)rhp << 4) + kcs) << 6 | lane_s) << 3 | jpos;
    *(u32*)(hrot + off16) = 0u;
  }
  ++gen; bar_signal(flg, cg, gen);

  for (int t = 0; t < T; ++t) {
    const u16* hin = hrot + (size_t)(t & (ROT - 1)) * BUFN;
    u16* hout = hrot + (size_t)((t + 1) & (ROT - 1)) * BUFN;

    if (tid < ROWS) {
      int row = row0 + tid;
      idsL[tid] = IS_TOK ? idsA[row * T + t]
                         : ((row < BATCH) ? idsA[row * T + t] : idsB[(row - BATCH) * T + t]);
    }
    __syncthreads();

    f32x4 acc[RPW][2];
    #pragma unroll
    for (int p = 0; p < RPW; ++p) {
      acc[p][0] = (f32x4){0.f, 0.f, 0.f, 0.f};
      acc[p][1] = (f32x4){0.f, 0.f, 0.f, 0.f};
    }
    const u16* eb[RPW];
    const u16* hfb[RPW];
    #pragma unroll
    for (int p = 0; p < RPW; ++p) {
      int rhp = w + (p << 2);
      int ida = idsL[(rhp << 4) + (l & 15)];
      eb[p] = embB + (size_t)ida * EPAD + ((l >> 4) << 3);
      hfb[p] = hin + ((((size_t)rhp << 4) << 9) | (l << 3));
    }

    // ---- h-independent input-projection MFMAs first ----
    #pragma unroll
    for (int kc = 0; kc < KC_E; ++kc) {
      bf16x8 b0 = *(const bf16x8*)(WiF + ((((kc << 1) | 0) << 6 | l) << 3));
      bf16x8 b1 = *(const bf16x8*)(WiF + ((((kc << 1) | 1) << 6 | l) << 3));
      #pragma unroll
      for (int p = 0; p < RPW; ++p) {
        bf16x8 a = *(const bf16x8*)(eb[p] + (kc << 5));
        acc[p][0] = __builtin_amdgcn_mfma_f32_16x16x32_bf16(a, b0, acc[p][0], 0, 0, 0);
        acc[p][1] = __builtin_amdgcn_mfma_f32_16x16x32_bf16(a, b1, acc[p][1], 0, 0, 0);
      }
    }

    // ---- wait for h(t-1) (wave0's vmem FIFO is clean: no slow stores issued) ----
    bar_wait(flg, gen);

    // ---- recurrent MFMAs from plain cached 16B loads (XCD-L2 hits) ----
    #pragma unroll
    for (int kc = 0; kc < KC_H; ++kc) {
      bf16x8 b0 = *(const bf16x8*)(WhF + ((((kc << 1) | 0) << 6 | l) << 3));
      bf16x8 b1 = *(const bf16x8*)(WhF + ((((kc << 1) | 1) << 6 | l) << 3));
      #pragma unroll
      for (int p = 0; p < RPW; ++p) {
        bf16x8 a = *(const bf16x8*)(hfb[p] + (kc << 9));
        acc[p][0] = __builtin_amdgcn_mfma_f32_16x16x32_bf16(a, b0, acc[p][0], 0, 0, 0);
        acc[p][1] = __builtin_amdgcn_mfma_f32_16x16x32_bf16(a, b1, acc[p][1], 0, 0, 0);
      }
    }

    // ---- epilogue: gates, c/h update; h store (L2-fast); feat -> LDS only ----
    #pragma unroll
    for (int p = 0; p < RPW; ++p) {
      int lr0 = (w << 4) + ((l >> 4) << 2);
      #pragma unroll
      for (int si = 0; si < 2; ++si)
        #pragma unroll
        for (int j = 0; j < 4; ++j)
          gsum[(lr0 + j) * 36 + (si << 4) + (l & 15)] = acc[p][si][j];
      __syncthreads();
      {
        float4 g0 = *(const float4*)&gsum[rl * 36 + (u << 2)];
        float4 g1 = *(const float4*)&gsum[rl * 36 + ((u + 4) << 2)];
        int lrow = (p << 6) + rl;
        int row = row0 + lrow;
        float gi0 = fsig(g0.x + bsv[0][0]);
        float gf0 = fsig(g0.y + bsv[0][1]);
        float gg0 = ftanh(g0.z + bsv[0][2]);
        float go0 = fsig(g0.w + bsv[0][3]);
        float cn0 = gf0 * cc[p][0] + gi0 * gg0;
        cc[p][0] = cn0;
        float hn0 = go0 * ftanh(cn0);
        float gi1 = fsig(g1.x + bsv[1][0]);
        float gf1 = fsig(g1.y + bsv[1][1]);
        float gg1 = ftanh(g1.z + bsv[1][2]);
        float go1 = fsig(g1.w + bsv[1][3]);
        float cn1 = gf1 * cc[p][1] + gi1 * gg1;
        cc[p][1] = cn1;
        float hn1 = go1 * ftanh(cn1);
        int rhp = lrow >> 4;
        int lane_s = (rl & 15) | (lanehi << 4);
        size_t off16 = ((((size_t)rhp << 4) + kcs) << 6 | lane_s) << 3 | jpos;
        *(u32*)(hout + off16) = (u32)f2bf(hn0) | ((u32)f2bf(hn1) << 16);
        if constexpr (IS_TOK) {
          featS[tid] = (u32)f2bf(ftanh(hn0)) | ((u32)f2bf(ftanh(hn1)) << 16);
        } else {
          if (t == lens[p] - 1) {
            finals[((size_t)row << 9) + ug0]     = ftanh(hn0);
            finals[((size_t)row << 9) + ug0 + 1] = ftanh(hn1);
          }
        }
      }
      __syncthreads();
    }
    ++gen; bar_signal(flg, cg, gen);   // vmcnt0 here drains only fast L2 h-stores

    if constexpr (IS_TOK) {
      // feat global stores by waves 1-3 ONLY (wave 0 stays store-free for its poll).
      if (tid >= 64) {
        for (int s = tid - 64; s < 256; s += 192) {
          int row = row0 + (s >> 2);
          int sug = (cg << 3) + ((s & 3) << 1);
          size_t fo = ((size_t)row * TCc + t) << 9;
          *(u32*)(featB + fo + sug) = featS[s];
        }
      }
    }
  }
}

// 512 blocks; each claims (xcd, rank). 2 blocks/CU -> exactly 64 blocks/XCD.
__global__ void __launch_bounds__(256, 1) lstm_persist_kernel(PArgs A) {
  __shared__ __align__(16) u16 WhF[KC_H * 2 * 64 * 8];   // 32768 B
  __shared__ __align__(16) u16 WiF[KC_E * 2 * 64 * 8];   // 20480 B
  __shared__ __align__(16) float gsum[64 * 36];          // 9216 B
  __shared__ int idsL[128];                              // 512 B
  __shared__ u32 featS[256];                             // 1024 B
  __shared__ int s_claim[2];
  if (threadIdx.x == 0) {
    int xcd;
    asm("s_getreg_b32 %0, hwreg(HW_REG_XCC_ID)" : "=s"(xcd));
    xcd &= 7;
    u32 rank = l2_add(A.flags + 8192 + (xcd << 4), 1u);
    s_claim[0] = xcd;
    s_claim[1] = (int)rank;
  }
  __syncthreads();
  const int xcd = s_claim[0];
  const int cg = s_claim[1] & 63;

  if (xcd < 4) {
    int rg = xcd;
    u32* flg = A.flags + (rg << 10);
    u16* hrot = A.hTok + (size_t)rg * ROT * ((size_t)64 << 9);
    lstm_phase<64, true>(cg, rg, WhF, WiF, gsum, idsL, featS, A.WhhT, A.WihT, A.embT,
                         A.tokens, nullptr, nullptr, nullptr,
                         A.tok_bih, A.tok_bhh, hrot, A.featB, nullptr,
                         flg, TCc);
  } else {
    int rg = xcd - 4;
    u32* flg = A.flags + ((4 + rg) << 10);
    u16* hrot = A.hDesc + (size_t)rg * ROT * ((size_t)128 << 9);
    lstm_phase<128, false>(cg, rg, WhF, WiF, gsum, idsL, featS, A.WhhD, A.WihD, A.embD,
                           A.desc_anchor, A.desc_neg, A.desc_anchor_len, A.desc_neg_len,
                           A.desc_bih, A.desc_bhh, hrot, nullptr, A.finals,
                           flg, TDc);
  }
}

// ---------------- attention scores via MFMA ----------------
__global__ __launch_bounds__(256) void attn_scores_mfma(
    const u16* __restrict__ featB, const u32* __restrict__ WF,
    const float* __restrict__ attn_b, const float* __restrict__ attnS_W,
    const float* __restrict__ attnS_b, float* __restrict__ scores)
{
  __shared__ __align__(16) u16 Af[4 * 16 * 64 * 8];   // 65536 B
  const int tid = threadIdx.x;
  const int m0 = blockIdx.x * 64;

  #pragma unroll
  for (int i = 0; i < 16; ++i) {
    int c = (i << 8) + tid;
    int r = c >> 6, kb = c & 63;
    uint4 v = *(const uint4*)(featB + (((size_t)(m0 + r)) << 9) + (kb << 3));
    int kc = kb >> 2, lf = (r & 15) + ((kb & 3) << 4);
    *(uint4*)(Af + ((((r >> 4) * 16 + kc) << 6 | lf) << 3)) = v;
  }
  __syncthreads();

  const int w = tid >> 6, l = tid & 63;
  const u16* WF16 = (const u16*)WF;
  float p[4][4] = {};
  for (int nc = w * 4; nc < w * 4 + 4; ++nc) {
    f32x4 acc[4][2];
    #pragma unroll
    for (int rh = 0; rh < 4; ++rh) {
      acc[rh][0] = (f32x4){0.f, 0.f, 0.f, 0.f};
      acc[rh][1] = (f32x4){0.f, 0.f, 0.f, 0.f};
    }
    #pragma unroll 4
    for (int kc = 0; kc < 16; ++kc) {
      bf16x8 b0 = *(const bf16x8*)(WF16 + ((size_t)((((nc << 4) + kc) << 1 | 0) << 6 | l) << 3));
      bf16x8 b1 = *(const bf16x8*)(WF16 + ((size_t)((((nc << 4) + kc) << 1 | 1) << 6 | l) << 3));
      #pragma unroll
      for (int rh = 0; rh < 4; ++rh) {
        bf16x8 a = *(const bf16x8*)(Af + (((rh * 16 + kc) << 6 | l) << 3));
        acc[rh][0] = __builtin_amdgcn_mfma_f32_16x16x32_bf16(a, b0, acc[rh][0], 0, 0, 0);
        acc[rh][1] = __builtin_amdgcn_mfma_f32_16x16x32_bf16(a, b1, acc[rh][1], 0, 0, 0);
      }
    }
    int c0 = (nc << 5) + (l & 15), c1 = c0 + 16;
    float bb0 = attn_b[c0], sw0 = attnS_W[c0];
    float bb1 = attn_b[c1], sw1 = attnS_W[c1];
    #pragma unroll
    for (int rh = 0; rh < 4; ++rh)
      #pragma unroll
      for (int j = 0; j < 4; ++j)
        p[rh][j] += tanhf(acc[rh][0][j] + bb0) * sw0 + tanhf(acc[rh][1][j] + bb1) * sw1;
  }
  __syncthreads();
  float* red = (float*)Af;   // 64 x 68
  #pragma unroll
  for (int rh = 0; rh < 4; ++rh)
    #pragma unroll
    for (int j = 0; j < 4; ++j)
      red[(rh * 16 + ((l >> 4) << 2) + j) * 68 + (w << 4) + (l & 15)] = p[rh][j];
  __syncthreads();
  if (tid < 64) {
    float s = attnS_b[0];
    #pragma unroll 8
    for (int q = 0; q < 64; ++q) s += red[tid * 68 + q];
    scores[m0 + tid] = s;
  }
}

// masked softmax over T=200 + weighted pooling of bf16 feat -> pooled (B,H) fp32
__global__ __launch_bounds__(256) void softmax_pool_kernel(
    const float* __restrict__ scores, const int* __restrict__ tok_len,
    const u16* __restrict__ featB, float* __restrict__ pooled)
{
  const int b = blockIdx.x;
  const int tid = threadIdx.x;
  __shared__ float wgt[TCc];
  __shared__ float red[256];
  const int len = tok_len[b];

  float myv = -1e30f;
  if (tid < TCc) {
    float s = scores[b * TCc + tid];
    myv = (tid < len) ? s : -1e9f;
    wgt[tid] = myv;
  }
  red[tid] = myv;
  __syncthreads();
  for (int s = 128; s > 0; s >>= 1) {
    if (tid < s) red[tid] = fmaxf(red[tid], red[tid + s]);
    __syncthreads();
  }
  const float mx = red[0];
  __syncthreads();
  float e = 0.f;
  if (tid < TCc) e = expf(wgt[tid] - mx);
  red[tid] = e;
  __syncthreads();
  for (int s = 128; s > 0; s >>= 1) {
    if (tid < s) red[tid] += red[tid + s];
    __syncthreads();
  }
  const float sum = red[0];
  __syncthreads();
  if (tid < TCc) wgt[tid] = e / sum;
  __syncthreads();

  const u32* featU = (const u32*)featB;
  float a0 = 0.f, a1 = 0.f;
  for (int t = 0; t < TCc; ++t) {
    u32 v = featU[((size_t)b * TCc + t) * 256 + tid];
    float wv = wgt[t];
    a0 = fmaf(wv, bf2f((u16)(v & 0xFFFF)), a0);
    a1 = fmaf(wv, bf2f((u16)(v >> 16)), a1);
  }
  pooled[((size_t)b << 9) + tid * 2] = a0;
  pooled[((size_t)b << 9) + tid * 2 + 1] = a1;
}

// C[m,n] = tanh(A[m,:] . W[n,:] + bias[n]); fp32, grid (M/64, N/64)
__global__ __launch_bounds__(256) void gemm_bias_tanh_kernel(
    const float* __restrict__ A, const float* __restrict__ Bw,
    const float* __restrict__ bias, float* __restrict__ C, int M, int N, int K)
{
  const int r0 = blockIdx.x * 64;
  const int n0 = blockIdx.y * 64;
  const int tid = threadIdx.x;
  const int tu = tid & 15;
  const int tm = tid >> 4;
  __shared__ float As[32][68];
  __shared__ float Bs[32][68];

  float acc[4][4] = {};
  for (int k0 = 0; k0 < K; k0 += 32) {
    #pragma unroll
    for (int i = 0; i < 2; ++i) {
      int lin = tid + (i << 8);
      int kq = lin & 7, m = lin >> 3;
      int k = k0 + (kq << 2);
      int r = r0 + m; if (r >= M) r = M - 1;
      float4 va = *(const float4*)&A[(size_t)r * K + k];
      float4 vb = *(const float4*)&Bw[(size_t)(n0 + m) * K + k];
      As[(kq << 2) + 0][m] = va.x; As[(kq << 2) + 1][m] = va.y;
      As[(kq << 2) + 2][m] = va.z; As[(kq << 2) + 3][m] = va.w;
      Bs[(kq << 2) + 0][m] = vb.x; Bs[(kq << 2) + 1][m] = vb.y;
      Bs[(kq << 2) + 2][m] = vb.z; Bs[(kq << 2) + 3][m] = vb.w;
    }
    __syncthreads();
    #pragma unroll
    for (int kk = 0; kk < 32; ++kk) {
      float4 a = *(const float4*)&As[kk][tm << 2];
      float4 b = *(const float4*)&Bs[kk][tu << 2];
      acc[0][0] = fmaf(a.x, b.x, acc[0][0]); acc[0][1] = fmaf(a.x, b.y, acc[0][1]);
      acc[0][2] = fmaf(a.x, b.z, acc[0][2]); acc[0][3] = fmaf(a.x, b.w, acc[0][3]);
      acc[1][0] = fmaf(a.y, b.x, acc[1][0]); acc[1][1] = fmaf(a.y, b.y, acc[1][1]);
      acc[1][2] = fmaf(a.y, b.z, acc[1][2]); acc[1][3] = fmaf(a.y, b.w, acc[1][3]);
      acc[2][0] = fmaf(a.z, b.x, acc[2][0]); acc[2][1] = fmaf(a.z, b.y, acc[2][1]);
      acc[2][2] = fmaf(a.z, b.z, acc[2][2]); acc[2][3] = fmaf(a.z, b.w, acc[2][3]);
      acc[3][0] = fmaf(a.w, b.x, acc[3][0]); acc[3][1] = fmaf(a.w, b.y, acc[3][1]);
      acc[3][2] = fmaf(a.w, b.z, acc[3][2]); acc[3][3] = fmaf(a.w, b.w, acc[3][3]);
    }
    __syncthreads();
  }
  float bj[4];
  #pragma unroll
  for (int j = 0; j < 4; ++j) bj[j] = bias[n0 + (tu << 2) + j];
  #pragma unroll
  for (int i = 0; i < 4; ++i) {
    int r = r0 + (tm << 2) + i;
    if (r < M) {
      float4 v;
      v.x = tanhf(acc[i][0] + bj[0]); v.y = tanhf(acc[i][1] + bj[1]);
      v.z = tanhf(acc[i][2] + bj[2]); v.w = tanhf(acc[i][3] + bj[3]);
      *(float4*)&C[(size_t)r * N + n0 + (tu << 2)] = v;
    }
  }
}

__global__ __launch_bounds__(256) void loss_kernel(
    const float* __restrict__ code, const float* __restrict__ finals, float* __restrict__ out)
{
  const int b = threadIdx.x;
  const float* cv = code + (size_t)b * Hc;
  const float* av = finals + (size_t)b * Hc;
  const float* nv = finals + (size_t)(BATCH + b) * Hc;
  float dca = 0, dcn = 0, ncc = 0, naa = 0, nnn = 0;
  for (int k = 0; k < Hc; ++k) {
    float c = cv[k], a = av[k], n = nv[k];
    dca = fmaf(c, a, dca);
    dcn = fmaf(c, n, dcn);
    ncc = fmaf(c, c, ncc);
    naa = fmaf(a, a, naa);
    nnn = fmaf(n, n, nnn);
  }
  float cos_a = dca / fmaxf(sqrtf(ncc) * sqrtf(naa), 1e-8f);
  float cos_n = dcn / fmaxf(sqrtf(ncc) * sqrtf(nnn), 1e-8f);
  float hinge = fmaxf(0.6f - cos_a + cos_n, 1e-6f);
  __shared__ float red[256];
  red[b] = hinge;
  __syncthreads();
  for (int s = 128; s > 0; s >>= 1) {
    if (b < s) red[b] += red[b + s];
    __syncthreads();
  }
  if (b == 0) out[0] = red[0] / 256.0f;
}

extern "C" void kernel_launch(void* const* d_in, const int* in_sizes, int n_in,
                              void* d_out, int out_size, void* d_ws, size_t ws_size,
                              hipStream_t stream) {
  const int* tokens          = (const int*)d_in[0];
  const int* tok_len         = (const int*)d_in[1];
  const int* desc_anchor     = (const int*)d_in[2];
  const int* desc_anchor_len = (const int*)d_in[3];
  const int* desc_neg        = (const int*)d_in[4];
  const int* desc_neg_len    = (const int*)d_in[5];
  const float* tok_emb  = (const float*)d_in[6];
  const float* tok_Wih  = (const float*)d_in[7];
  const float* tok_Whh  = (const float*)d_in[8];
  const float* tok_bih  = (const float*)d_in[9];
  const float* tok_bhh  = (const float*)d_in[10];
  const float* desc_emb = (const float*)d_in[11];
  const float* desc_Wih = (const float*)d_in[12];
  const float* desc_Whh = (const float*)d_in[13];
  const float* desc_bih = (const float*)d_in[14];
  const float* desc_bhh = (const float*)d_in[15];
  const float* attn_W   = (const float*)d_in[16];
  const float* attn_b   = (const float*)d_in[17];
  const float* attnS_W  = (const float*)d_in[18];
  const float* attnS_b  = (const float*)d_in[19];
  const float* out_W1   = (const float*)d_in[20];
  const float* out_b1   = (const float*)d_in[21];
  const float* out_W2   = (const float*)d_in[22];
  const float* out_b2   = (const float*)d_in[23];

  float* p = (float*)d_ws;
  size_t off = 0;
  auto alloc = [&](size_t n) { float* q = p + off; off += n; return q; };

  u16*  featB  = (u16*)alloc(13107200);
  u16*  embT   = (u16*)alloc(1600000);
  u16*  embD   = (u16*)alloc(1600000);
  u32*  WihT   = (u32*)alloc(327680);
  u32*  WihD   = (u32*)alloc(327680);
  u32*  WhhT   = (u32*)alloc(524288);
  u32*  WhhD   = (u32*)alloc(524288);
  u32*  attnWF = (u32*)alloc(131072);
  u16*  hTok   = (u16*)alloc(1048576);
  u16*  hDesc  = (u16*)alloc(2097152);
  float* finals = alloc(262144);
  float* scores = alloc(51200);
  float* pooled = alloc(131072);
  float* a2     = alloc(131072);
  float* code   = alloc(131072);
  u32* flags = (u32*)alloc(8320);

  conv_emb_kernel<<<(VOC * (EPAD / 2) + 255) / 256, 256, 0, stream>>>(tok_emb, (u32*)embT);
  conv_emb_kernel<<<(VOC * (EPAD / 2) + 255) / 256, 256, 0, stream>>>(desc_emb, (u32*)embD);
  conv_wfrag_kernel<1><<<2048, 256, 0, stream>>>(tok_Whh, WhhT, KC_H, Hc, 524288);
  conv_wfrag_kernel<1><<<2048, 256, 0, stream>>>(desc_Whh, WhhD, KC_H, Hc, 524288);
  conv_wfrag_kernel<1><<<1280, 256, 0, stream>>>(tok_Wih, WihT, KC_E, Ec, 327680);
  conv_wfrag_kernel<1><<<1280, 256, 0, stream>>>(desc_Wih, WihD, KC_E, Ec, 327680);
  conv_wfrag_kernel<0><<<512, 256, 0, stream>>>(attn_W, attnWF, KC_H, Hc, 131072);
  zero_kernel<<<33, 256, 0, stream>>>((float*)flags, 8320);

  PArgs A;
  A.WhhT = WhhT; A.WihT = WihT; A.embT = embT;
  A.WhhD = WhhD; A.WihD = WihD; A.embD = embD;
  A.tokens = tokens; A.desc_anchor = desc_anchor; A.desc_neg = desc_neg;
  A.desc_anchor_len = desc_anchor_len; A.desc_neg_len = desc_neg_len;
  A.tok_bih = tok_bih; A.tok_bhh = tok_bhh;
  A.desc_bih = desc_bih; A.desc_bhh = desc_bhh;
  A.hTok = hTok; A.hDesc = hDesc;
  A.featB = featB; A.finals = finals; A.flags = flags;
  lstm_persist_kernel<<<512, 256, 0, stream>>>(A);

  attn_scores_mfma<<<(BATCH * TCc) / 64, 256, 0, stream>>>(
      featB, attnWF, attn_b, attnS_W, attnS_b, scores);
  softmax_pool_kernel<<<BATCH, 256, 0, stream>>>(scores, tok_len, featB, pooled);
  gemm_bias_tanh_kernel<<<dim3(BATCH / 64, Hc / 64), 256, 0, stream>>>(
      pooled, out_W1, out_b1, a2, BATCH, Hc, Hc);
  gemm_bias_tanh_kernel<<<dim3(BATCH / 64, Hc / 64), 256, 0, stream>>>(
      a2, out_W2, out_b2, code, BATCH, Hc, Hc);
  loss_kernel<<<1, 256, 0, stream>>>(code, finals, (float*)d_out);
}